// Round 1
// baseline (663.451 us; speedup 1.0000x reference)
//
#include <hip/hip_runtime.h>
#include <math.h>

// Problem constants (fixed by the reference)
#define N   32
#define DM  256
#define H   64
#define BT  8192          // 16*512 rows
#define T_SEQ 512

// ---------------------------------------------------------------------------
// Kernel 0: transpose f_gate_w / f_fc2_w from [n][d][h] to [n][h][d] so that
// the heavy kernel's weight loads are coalesced (lane = d).
// grid.x = 32 n * 4 d-tiles, grid.y = 2 tensors, 256 threads.
// ---------------------------------------------------------------------------
__global__ void k_tr(const float* __restrict__ s0, float* __restrict__ d0,
                     const float* __restrict__ s1, float* __restrict__ d1) {
    const float* src = blockIdx.y ? s1 : s0;
    float*       dst = blockIdx.y ? d1 : d0;
    int n  = blockIdx.x >> 2;
    int dt = blockIdx.x & 3;
    __shared__ float tile[64][65];   // +1 pad: conflict-free transpose
    int t = threadIdx.x;
    const float* sp = src + n * DM * H + dt * 64 * H;
#pragma unroll
    for (int i = 0; i < 16; i++) {
        int flat = i * 256 + t;
        int dl = flat >> 6, hh = flat & 63;
        tile[dl][hh] = sp[dl * H + hh];          // coalesced read
    }
    __syncthreads();
    float* dp = dst + n * H * DM + dt * 64;
#pragma unroll
    for (int i = 0; i < 16; i++) {
        int flat = i * 256 + t;
        int hl = flat >> 6, dl = flat & 63;
        dp[hl * DM + dl] = tile[dl][hl];         // coalesced write
    }
}

// ---------------------------------------------------------------------------
// Kernel 1: selection GRN -> softmax weights [BT][N] into ws, plus
// feat_weights accumulation (atomicAdd, scaled 1/512) into d_out tail.
// One row per block, 256 threads.
// ---------------------------------------------------------------------------
__global__ void k_sel(const float* __restrict__ x,
                      const float* __restrict__ fc1w, const float* __restrict__ fc1b,
                      const float* __restrict__ gatew, const float* __restrict__ gateb,
                      const float* __restrict__ fc2w, const float* __restrict__ fc2b,
                      const float* __restrict__ lng, const float* __restrict__ lnb,
                      float* __restrict__ wsel, float* __restrict__ fwout) {
    int row = blockIdx.x;
    int t = threadIdx.x;
    __shared__ float xr[N];
    __shared__ float h[DM];
    __shared__ float pa[N][8];
    __shared__ float ph[N][8];
    __shared__ float yv[64];

    if (t < N) xr[t] = x[row * N + t];
    __syncthreads();

    // h[dm] = elu(x . fc1w[dm,:] + b), one dm per thread
    {
        const float4* wrow = (const float4*)(fc1w + t * N);
        float acc = fc1b[t];
#pragma unroll
        for (int c = 0; c < 8; c++) {
            float4 wv = wrow[c];
            acc += wv.x * xr[c * 4 + 0] + wv.y * xr[c * 4 + 1]
                 + wv.z * xr[c * 4 + 2] + wv.w * xr[c * 4 + 3];
        }
        h[t] = acc > 0.f ? acc : expf(acc) - 1.f;
    }
    __syncthreads();

    // a[n], h2[n]: 8 partial-threads per n over dm
    {
        int n = t >> 3, k = t & 7;
        const float4* gr = (const float4*)(gatew + n * DM + k * 32);
        const float4* fr = (const float4*)(fc2w + n * DM + k * 32);
        const float4* hr = (const float4*)(h + k * 32);
        float a = 0.f, b = 0.f;
#pragma unroll
        for (int c = 0; c < 8; c++) {
            float4 hv = hr[c], gv = gr[c], fv = fr[c];
            a += gv.x * hv.x + gv.y * hv.y + gv.z * hv.z + gv.w * hv.w;
            b += fv.x * hv.x + fv.y * hv.y + fv.z * hv.z + fv.w * hv.w;
        }
        pa[n][k] = a;
        ph[n][k] = b;
    }
    __syncthreads();

    if (t < N) {
        float a = 0.f, b = 0.f;
#pragma unroll
        for (int k = 0; k < 8; k++) { a += pa[t][k]; b += ph[t][k]; }
        a = 1.f / (1.f + expf(-(a + gateb[t])));
        b = b + fc2b[t];
        yv[t] = a * b + xr[t];
    } else if (t < 64) {
        yv[t] = 0.f;
    }
    __syncthreads();

    // LN over 32 + softmax over 32, wave 0 (lanes 0..31 meaningful)
    if (t < 64) {
        float y = yv[t];
        float s1 = y, s2 = y * y;
#pragma unroll
        for (int m = 1; m < 32; m <<= 1) {
            s1 += __shfl_xor(s1, m);
            s2 += __shfl_xor(s2, m);
        }
        float mean = s1 * (1.f / 32.f);
        float var  = s2 * (1.f / 32.f) - mean * mean;
        float xn = (y - mean) * rsqrtf(var + 1e-5f) * lng[t & 31] + lnb[t & 31];
        float mx = xn;
#pragma unroll
        for (int m = 1; m < 32; m <<= 1) mx = fmaxf(mx, __shfl_xor(mx, m));
        float e = expf(xn - mx);
        float es = e;
#pragma unroll
        for (int m = 1; m < 32; m <<= 1) es += __shfl_xor(es, m);
        float w = e / es;
        if (t < N) {
            wsel[row * N + t] = w;
            atomicAdd(fwout + (row >> 9) * N + t, w * (1.f / (float)T_SEQ));
        }
    }
}

// ---------------------------------------------------------------------------
// Kernel 2: per-feature GRNs + LN + weighted sum -> selected [BT][DM].
// Block = 256 threads = 4 waves; wave owns 4 rows; lane owns 4 consecutive d.
// 16 rows per block -> 512 blocks. Weights read from L2 (transposed layout,
// coalesced); hf broadcast from LDS; LN is an intra-wave shuffle reduce.
// ---------------------------------------------------------------------------
__global__ __launch_bounds__(256, 2) void k_feat(
        const float* __restrict__ x,
        const float* __restrict__ f1w, const float* __restrict__ f1b,
        const float* __restrict__ gwT, const float* __restrict__ gb,
        const float* __restrict__ fwT, const float* __restrict__ fb,
        const float* __restrict__ skw, const float* __restrict__ skb,
        const float* __restrict__ lng, const float* __restrict__ lnb,
        const float* __restrict__ wsel, float* __restrict__ out) {
    __shared__ float xs[16][N];
    __shared__ float wss[16][N];
    __shared__ float hf[16][H];

    int t = threadIdx.x;
    int wid = t >> 6, lane = t & 63;
    int wid4 = wid * 4;
    int R0 = blockIdx.x * 16;

    // stage x rows and selection weights (contiguous, coalesced)
#pragma unroll
    for (int i = 0; i < 2; i++) {
        int idx = i * 256 + t;
        ((float*)xs)[idx]  = x[R0 * N + idx];
        ((float*)wss)[idx] = wsel[R0 * N + idx];
    }

    float sel[4][4];
#pragma unroll
    for (int r = 0; r < 4; r++)
#pragma unroll
        for (int dc = 0; dc < 4; dc++) sel[r][dc] = 0.f;

    for (int n = 0; n < N; n++) {
        __syncthreads();   // hf reuse from previous iter + first-iter staging
        // stage hf[16][64] = elu(x[r][n] * f1w[n][h] + f1b[n][h])
#pragma unroll
        for (int i = 0; i < 4; i++) {
            int idx = i * 256 + t;
            int r = idx >> 6, hh = idx & 63;
            float pre = xs[r][n] * f1w[n * H + hh] + f1b[n * H + hh];
            hf[r][hh] = pre > 0.f ? pre : expf(pre) - 1.f;
        }
        __syncthreads();

        // per-(n,d) constants, coalesced float4 loads
        float gbv[4], fbv[4], skwv[4], skbv[4], lngv[4], lnbv[4];
        {
            int off = n * DM + lane * 4;
            float4 v;
            v = *(const float4*)(gb  + off); gbv[0]=v.x; gbv[1]=v.y; gbv[2]=v.z; gbv[3]=v.w;
            v = *(const float4*)(fb  + off); fbv[0]=v.x; fbv[1]=v.y; fbv[2]=v.z; fbv[3]=v.w;
            v = *(const float4*)(skw + off); skwv[0]=v.x; skwv[1]=v.y; skwv[2]=v.z; skwv[3]=v.w;
            v = *(const float4*)(skb + off); skbv[0]=v.x; skbv[1]=v.y; skbv[2]=v.z; skbv[3]=v.w;
            v = *(const float4*)(lng + off); lngv[0]=v.x; lngv[1]=v.y; lngv[2]=v.z; lngv[3]=v.w;
            v = *(const float4*)(lnb + off); lnbv[0]=v.x; lnbv[1]=v.y; lnbv[2]=v.z; lnbv[3]=v.w;
        }

        float af[4][4], h2[4][4];
#pragma unroll
        for (int r = 0; r < 4; r++)
#pragma unroll
            for (int dc = 0; dc < 4; dc++) { af[r][dc] = gbv[dc]; h2[r][dc] = fbv[dc]; }

        const float* gptr = gwT + n * H * DM + lane * 4;
        const float* fptr = fwT + n * H * DM + lane * 4;
#pragma unroll 4
        for (int h = 0; h < H; h += 4) {
            float4 g0 = *(const float4*)(gptr + (h + 0) * DM);
            float4 g1 = *(const float4*)(gptr + (h + 1) * DM);
            float4 g2 = *(const float4*)(gptr + (h + 2) * DM);
            float4 g3 = *(const float4*)(gptr + (h + 3) * DM);
            float4 f0 = *(const float4*)(fptr + (h + 0) * DM);
            float4 f1 = *(const float4*)(fptr + (h + 1) * DM);
            float4 f2 = *(const float4*)(fptr + (h + 2) * DM);
            float4 f3 = *(const float4*)(fptr + (h + 3) * DM);
#pragma unroll
            for (int r = 0; r < 4; r++) {
                float4 hv = *(const float4*)(&hf[wid4 + r][h]);  // wave-uniform broadcast
                af[r][0] += hv.x * g0.x + hv.y * g1.x + hv.z * g2.x + hv.w * g3.x;
                af[r][1] += hv.x * g0.y + hv.y * g1.y + hv.z * g2.y + hv.w * g3.y;
                af[r][2] += hv.x * g0.z + hv.y * g1.z + hv.z * g2.z + hv.w * g3.z;
                af[r][3] += hv.x * g0.w + hv.y * g1.w + hv.z * g2.w + hv.w * g3.w;
                h2[r][0] += hv.x * f0.x + hv.y * f1.x + hv.z * f2.x + hv.w * f3.x;
                h2[r][1] += hv.x * f0.y + hv.y * f1.y + hv.z * f2.y + hv.w * f3.y;
                h2[r][2] += hv.x * f0.z + hv.y * f1.z + hv.z * f2.z + hv.w * f3.z;
                h2[r][3] += hv.x * f0.w + hv.y * f1.w + hv.z * f2.w + hv.w * f3.w;
            }
        }

        // epilogue: sigmoid gate, skip, LayerNorm over d (intra-wave), accumulate
#pragma unroll
        for (int r = 0; r < 4; r++) {
            int rr = wid4 + r;
            float xv = xs[rr][n];     // wave-uniform broadcast
            float y[4];
            float s1 = 0.f, s2 = 0.f;
#pragma unroll
            for (int dc = 0; dc < 4; dc++) {
                float a = 1.f / (1.f + expf(-af[r][dc]));
                float yy = a * h2[r][dc] + xv * skwv[dc] + skbv[dc];
                y[dc] = yy;
                s1 += yy;
                s2 += yy * yy;
            }
#pragma unroll
            for (int m = 1; m < 64; m <<= 1) {
                s1 += __shfl_xor(s1, m);
                s2 += __shfl_xor(s2, m);
            }
            float mean = s1 * (1.f / (float)DM);
            float var  = s2 * (1.f / (float)DM) - mean * mean;
            float rs = rsqrtf(var + 1e-5f);
            float w = wss[rr][n];     // wave-uniform broadcast
#pragma unroll
            for (int dc = 0; dc < 4; dc++) {
                float proc = (y[dc] - mean) * rs * lngv[dc] + lnbv[dc];
                sel[r][dc] += proc * w;
            }
        }
    }

    // write selected, coalesced float4 per row
#pragma unroll
    for (int r = 0; r < 4; r++) {
        int row = R0 + wid4 + r;
        float4 v;
        v.x = sel[r][0]; v.y = sel[r][1]; v.z = sel[r][2]; v.w = sel[r][3];
        *(float4*)(out + row * DM + lane * 4) = v;
    }
}

// ---------------------------------------------------------------------------
extern "C" void kernel_launch(void* const* d_in, const int* in_sizes, int n_in,
                              void* d_out, int out_size, void* d_ws, size_t ws_size,
                              hipStream_t stream) {
    const float* x        = (const float*)d_in[0];
    const float* g_fc1_w  = (const float*)d_in[1];
    const float* g_fc1_b  = (const float*)d_in[2];
    const float* g_gate_w = (const float*)d_in[3];
    const float* g_gate_b = (const float*)d_in[4];
    const float* g_fc2_w  = (const float*)d_in[5];
    const float* g_fc2_b  = (const float*)d_in[6];
    const float* g_ln_g   = (const float*)d_in[7];
    const float* g_ln_b   = (const float*)d_in[8];
    const float* f_fc1_w  = (const float*)d_in[9];
    const float* f_fc1_b  = (const float*)d_in[10];
    const float* f_gate_w = (const float*)d_in[11];
    const float* f_gate_b = (const float*)d_in[12];
    const float* f_fc2_w  = (const float*)d_in[13];
    const float* f_fc2_b  = (const float*)d_in[14];
    const float* f_skip_w = (const float*)d_in[15];
    const float* f_skip_b = (const float*)d_in[16];
    const float* f_ln_g   = (const float*)d_in[17];
    const float* f_ln_b   = (const float*)d_in[18];

    float* out_sel = (float*)d_out;                    // [8192][256]
    float* out_fw  = (float*)d_out + BT * DM;          // [16][32]

    // workspace layout (needs 5 MB):
    float* ws_w = (float*)d_ws;                        // [8192][32]  weights
    float* gwT  = ws_w + BT * N;                       // [32][64][256]
    float* fwT  = gwT + N * H * DM;                    // [32][64][256]

    // feat_weights accumulated via atomics -> zero it (d_ws/d_out are poisoned)
    hipMemsetAsync(out_fw, 0, 16 * N * sizeof(float), stream);

    k_tr<<<dim3(N * 4, 2), 256, 0, stream>>>(f_gate_w, gwT, f_fc2_w, fwT);

    k_sel<<<BT, 256, 0, stream>>>(x, g_fc1_w, g_fc1_b, g_gate_w, g_gate_b,
                                  g_fc2_w, g_fc2_b, g_ln_g, g_ln_b,
                                  ws_w, out_fw);

    k_feat<<<BT / 16, 256, 0, stream>>>(x, f_fc1_w, f_fc1_b,
                                        gwT, f_gate_b, fwT, f_fc2_b,
                                        f_skip_w, f_skip_b, f_ln_g, f_ln_b,
                                        ws_w, out_sel);
}

// Round 3
// 393.645 us; speedup vs baseline: 1.6854x; 1.6854x over previous
//
#include <hip/hip_runtime.h>
#include <math.h>

// Problem constants (fixed by the reference)
#define N   32
#define DM  256
#define H   64
#define BT  8192          // 16*512 rows
#define T_SEQ 512

typedef __attribute__((ext_vector_type(8))) short bf16x8;   // 8 bf16 = 4 VGPR
typedef __attribute__((ext_vector_type(4))) float f32x4;    // MFMA acc

__device__ __forceinline__ float elu_f(float v) {
    // elu(v) = v>0 ? v : exp(v)-1 ; exp(x)-1 >= x so fmax works branchlessly
    return fmaxf(v, __expf(fminf(v, 0.f)) - 1.f);
}
__device__ __forceinline__ float sigm_f(float v) {
    return 1.f / (1.f + __expf(-v));
}

// split v into truncated-bf16 hi + truncated-bf16 lo (lo = exact residual of hi)
__device__ __forceinline__ void split_pack8(const float* v, bf16x8& hi, bf16x8& lo) {
    unsigned u[8]; float lf[8];
#pragma unroll
    for (int i = 0; i < 8; i++) {
        u[i]  = __builtin_bit_cast(unsigned, v[i]);
        lf[i] = v[i] - __builtin_bit_cast(float, u[i] & 0xffff0000u);
    }
    unsigned hw[4], lw[4];
#pragma unroll
    for (int j = 0; j < 4; j++) {
        hw[j] = (u[2*j] >> 16) | (u[2*j+1] & 0xffff0000u);
        unsigned l0 = __builtin_bit_cast(unsigned, lf[2*j]);
        unsigned l1 = __builtin_bit_cast(unsigned, lf[2*j+1]);
        lw[j] = (l0 >> 16) | (l1 & 0xffff0000u);
    }
    uint4 h4 = make_uint4(hw[0], hw[1], hw[2], hw[3]);
    uint4 l4 = make_uint4(lw[0], lw[1], lw[2], lw[3]);
    hi = __builtin_bit_cast(bf16x8, h4);
    lo = __builtin_bit_cast(bf16x8, l4);
}

// ---------------------------------------------------------------------------
// k_pack: pack f_gate_w / f_fc2_w [N][DM][H] into per-(n,wc) MFMA B-fragments
// (hi/lo split). Fragment (n,wc,ks,ct,s): lane l holds col d = wc*64+(ct&3)*16
// +(l&15) (ct<4 -> gate, ct>=4 -> fc2), k = ks*32+(l>>4)*8+i, value W[n][d][k].
// Layout: ((((n*4+wc)*2+ks)*8+ct)*2+s)*512 + lane*8 + i   (bf16 elements)
// ---------------------------------------------------------------------------
__global__ __launch_bounds__(256) void k_pack(const float* __restrict__ gw,
                                              const float* __restrict__ fw,
                                              short* __restrict__ bfrag) {
    int n = blockIdx.x >> 2, wc = blockIdx.x & 3;
    int wid = threadIdx.x >> 6, lane = threadIdx.x & 63;
    for (int it = wid; it < 16; it += 4) {
        int ks = it >> 3, ct = it & 7;
        const float* W = (ct < 4) ? gw : fw;
        int d  = wc * 64 + (ct & 3) * 16 + (lane & 15);
        int h0 = ks * 32 + (lane >> 4) * 8;
        const float* src = W + (n * DM + d) * H + h0;
        float v[8];
        float4 a = *(const float4*)src;
        float4 b = *(const float4*)(src + 4);
        v[0]=a.x; v[1]=a.y; v[2]=a.z; v[3]=a.w;
        v[4]=b.x; v[5]=b.y; v[6]=b.z; v[7]=b.w;
        bf16x8 hi, lo;
        split_pack8(v, hi, lo);
        short* dst = bfrag + (size_t)((((n*4 + wc)*2 + ks)*8 + ct)*2) * 512 + lane * 8;
        *(bf16x8*)dst         = hi;
        *(bf16x8*)(dst + 512) = lo;
    }
}

// ---------------------------------------------------------------------------
// k_sel: selection GRN, one row per WAVE (4 rows / 256-thread block).
// ---------------------------------------------------------------------------
__global__ __launch_bounds__(256) void k_sel(const float* __restrict__ x,
                      const float* __restrict__ fc1w, const float* __restrict__ fc1b,
                      const float* __restrict__ gatew, const float* __restrict__ gateb,
                      const float* __restrict__ fc2w, const float* __restrict__ fc2b,
                      const float* __restrict__ lng, const float* __restrict__ lnb,
                      float* __restrict__ wsel, float* __restrict__ fwout) {
    int wid = threadIdx.x >> 6, lane = threadIdx.x & 63;
    int row = blockIdx.x * 4 + wid;
    int l31 = lane & 31;

    float xv = x[row * N + l31];

    // h[dm0..dm0+3] = elu(fc1w[dm] . x + fc1b[dm]), dm0 = lane*4
    int dm0 = lane * 4;
    float4 hb = *(const float4*)(fc1b + dm0);
    float h0 = hb.x, h1 = hb.y, h2 = hb.z, h3 = hb.w;
#pragma unroll
    for (int c4 = 0; c4 < 8; c4++) {
        float4 w0 = *(const float4*)(fc1w + (dm0 + 0) * N + c4 * 4);
        float4 w1 = *(const float4*)(fc1w + (dm0 + 1) * N + c4 * 4);
        float4 w2 = *(const float4*)(fc1w + (dm0 + 2) * N + c4 * 4);
        float4 w3 = *(const float4*)(fc1w + (dm0 + 3) * N + c4 * 4);
        float xb0 = __shfl(xv, c4 * 4 + 0);
        float xb1 = __shfl(xv, c4 * 4 + 1);
        float xb2 = __shfl(xv, c4 * 4 + 2);
        float xb3 = __shfl(xv, c4 * 4 + 3);
        h0 += w0.x * xb0 + w0.y * xb1 + w0.z * xb2 + w0.w * xb3;
        h1 += w1.x * xb0 + w1.y * xb1 + w1.z * xb2 + w1.w * xb3;
        h2 += w2.x * xb0 + w2.y * xb1 + w2.z * xb2 + w2.w * xb3;
        h3 += w3.x * xb0 + w3.y * xb1 + w3.z * xb2 + w3.w * xb3;
    }
    h0 = elu_f(h0); h1 = elu_f(h1); h2 = elu_f(h2); h3 = elu_f(h3);

    // a[n], h2[n] via per-n dot + full-wave butterfly reduce
    float av = 0.f, bv = 0.f;
#pragma unroll
    for (int nn = 0; nn < N; nn++) {
        float4 g = *(const float4*)(gatew + nn * DM + dm0);
        float4 f = *(const float4*)(fc2w  + nn * DM + dm0);
        float pa = g.x * h0 + g.y * h1 + g.z * h2 + g.w * h3;
        float pb = f.x * h0 + f.y * h1 + f.z * h2 + f.w * h3;
#pragma unroll
        for (int m = 1; m < 64; m <<= 1) {
            pa += __shfl_xor(pa, m);
            pb += __shfl_xor(pb, m);
        }
        if (l31 == nn) { av = pa; bv = pb; }
    }

    float a  = sigm_f(av + gateb[l31]);
    float b2 = bv + fc2b[l31];
    float y  = a * b2 + xv;

    // LN over 32 (halves of the wave are duplicates -> masks 1..16)
    float s1 = y, s2 = y * y;
#pragma unroll
    for (int m = 1; m < 32; m <<= 1) { s1 += __shfl_xor(s1, m); s2 += __shfl_xor(s2, m); }
    float mean = s1 * (1.f / 32.f);
    float var  = s2 * (1.f / 32.f) - mean * mean;
    float xn = (y - mean) * rsqrtf(var + 1e-5f) * lng[l31] + lnb[l31];
    float mx = xn;
#pragma unroll
    for (int m = 1; m < 32; m <<= 1) mx = fmaxf(mx, __shfl_xor(mx, m));
    float e = __expf(xn - mx);
    float es = e;
#pragma unroll
    for (int m = 1; m < 32; m <<= 1) es += __shfl_xor(es, m);
    float w = e / es;

    if (lane < 32) {
        wsel[row * N + l31] = w;
        atomicAdd(fwout + (row >> 9) * N + l31, w * (1.f / (float)T_SEQ));
    }
}

// ---------------------------------------------------------------------------
// k_feat: per-feature GRNs via split-bf16 MFMA.
// 256 blocks x 256 threads; block owns 32 rows; wave wc owns d-slice
// [wc*64, wc*64+64) carrying gate (ct 0..3) AND fc2 (ct 4..7) columns.
// ---------------------------------------------------------------------------
__global__ __launch_bounds__(256, 1) void k_feat(
        const float* __restrict__ x,
        const float* __restrict__ f1w, const float* __restrict__ f1b,
        const short* __restrict__ bfrag,
        const float* __restrict__ gb,  const float* __restrict__ fb,
        const float* __restrict__ skw, const float* __restrict__ skb,
        const float* __restrict__ lng, const float* __restrict__ lnb,
        const float* __restrict__ wsel, float* __restrict__ out) {
    __shared__ float  xs[32 * 33];
    __shared__ float  wss[32 * 33];
    __shared__ float2 part[4][32];
    __shared__ float2 stat[32];

    int t = threadIdx.x;
    int wc = t >> 6, lane = t & 63;
    int l15 = lane & 15, lg = lane >> 4;
    int R0 = blockIdx.x * 32;

    // stage x rows + selection weights
#pragma unroll
    for (int i = 0; i < 4; i++) {
        int idx = i * 256 + t;              // 0..1023
        int r = idx >> 5, c = idx & 31;
        xs[r * 33 + c]  = x[(R0 + r) * N + c];
        wss[r * 33 + c] = wsel[(R0 + r) * N + c];
    }
    __syncthreads();

    f32x4 sel[2][4];
#pragma unroll
    for (int rt = 0; rt < 2; rt++)
#pragma unroll
        for (int ct = 0; ct < 4; ct++) sel[rt][ct] = (f32x4)(0.f);

    const short* bwc = bfrag + (size_t)(wc * 2) * 8 * 2 * 512;

#pragma unroll 1
    for (int n = 0; n < N; n++) {
        // ---- per-(n,d) constants for this wave's d-slice
        int dbase = n * DM + wc * 64 + l15;
        float gbv[4], fbv[4], skwv[4], skbv[4], lngv[4], lnbv[4];
#pragma unroll
        for (int ct = 0; ct < 4; ct++) {
            gbv[ct]  = gb [dbase + ct * 16];
            fbv[ct]  = fb [dbase + ct * 16];
            skwv[ct] = skw[dbase + ct * 16];
            skbv[ct] = skb[dbase + ct * 16];
            lngv[ct] = lng[dbase + ct * 16];
            lnbv[ct] = lnb[dbase + ct * 16];
        }

        // ---- A fragments: hf = elu(x*f1w+f1b), split hi/lo  [ks][rt]
        bf16x8 ahi[2][2], alo[2][2];
#pragma unroll
        for (int ks = 0; ks < 2; ks++) {
            int h0 = ks * 32 + lg * 8;
            float4 w0 = *(const float4*)(f1w + n * H + h0);
            float4 w1 = *(const float4*)(f1w + n * H + h0 + 4);
            float4 b0 = *(const float4*)(f1b + n * H + h0);
            float4 b1 = *(const float4*)(f1b + n * H + h0 + 4);
#pragma unroll
            for (int rt = 0; rt < 2; rt++) {
                float xa = xs[(rt * 16 + l15) * 33 + n];
                float v[8];
                v[0] = elu_f(xa * w0.x + b0.x);
                v[1] = elu_f(xa * w0.y + b0.y);
                v[2] = elu_f(xa * w0.z + b0.z);
                v[3] = elu_f(xa * w0.w + b0.w);
                v[4] = elu_f(xa * w1.x + b1.x);
                v[5] = elu_f(xa * w1.y + b1.y);
                v[6] = elu_f(xa * w1.z + b1.z);
                v[7] = elu_f(xa * w1.w + b1.w);
                split_pack8(v, ahi[ks][rt], alo[ks][rt]);
            }
        }

        // ---- MFMA: acc[rt][ct] ; ct<4 gate (init gate bias), ct>=4 fc2
        f32x4 acc[2][8];
#pragma unroll
        for (int rt = 0; rt < 2; rt++)
#pragma unroll
            for (int ct = 0; ct < 8; ct++)
                acc[rt][ct] = (f32x4)(ct < 4 ? gbv[ct] : fbv[ct - 4]);

        const short* bn = bwc + (size_t)n * 4 * 2 * 8 * 2 * 512;
#pragma unroll
        for (int ks = 0; ks < 2; ks++) {
#pragma unroll
            for (int ct = 0; ct < 8; ct++) {
                const short* bp = bn + ((ks * 8 + ct) * 2) * 512 + lane * 8;
                bf16x8 bhi = *(const bf16x8*)bp;
                bf16x8 blo = *(const bf16x8*)(bp + 512);
#pragma unroll
                for (int rt = 0; rt < 2; rt++) {
                    acc[rt][ct] = __builtin_amdgcn_mfma_f32_16x16x32_bf16(ahi[ks][rt], bhi, acc[rt][ct], 0, 0, 0);
                    acc[rt][ct] = __builtin_amdgcn_mfma_f32_16x16x32_bf16(alo[ks][rt], bhi, acc[rt][ct], 0, 0, 0);
                    acc[rt][ct] = __builtin_amdgcn_mfma_f32_16x16x32_bf16(ahi[ks][rt], blo, acc[rt][ct], 0, 0, 0);
                }
            }
        }

        // ---- epilogue: y = sig(gate)*fc2 + x*skw+skb ; LN partials
#pragma unroll
        for (int rt = 0; rt < 2; rt++) {
#pragma unroll
            for (int r4 = 0; r4 < 4; r4++) {
                int rowl = rt * 16 + lg * 4 + r4;
                float xa = xs[rowl * 33 + n];
                float s1 = 0.f, s2 = 0.f;
#pragma unroll
                for (int ct = 0; ct < 4; ct++) {
                    float a  = sigm_f(acc[rt][ct][r4]);
                    float yy = a * acc[rt][ct + 4][r4] + xa * skwv[ct] + skbv[ct];
                    acc[rt][ct + 4][r4] = yy;   // keep y in acc storage
                    s1 += yy; s2 += yy * yy;
                }
#pragma unroll
                for (int m = 1; m < 16; m <<= 1) {
                    s1 += __shfl_xor(s1, m);
                    s2 += __shfl_xor(s2, m);
                }
                if (l15 == 0) part[wc][rowl] = make_float2(s1, s2);
            }
        }
        __syncthreads();
        if (t < 32) {
            float s1 = part[0][t].x + part[1][t].x + part[2][t].x + part[3][t].x;
            float s2 = part[0][t].y + part[1][t].y + part[2][t].y + part[3][t].y;
            float mean = s1 * (1.f / (float)DM);
            float var  = s2 * (1.f / (float)DM) - mean * mean;
            stat[t] = make_float2(mean, rsqrtf(var + 1e-5f));
        }
        __syncthreads();

        // ---- proc = LN(y)*g+b ; sel += proc * w
#pragma unroll
        for (int rt = 0; rt < 2; rt++) {
#pragma unroll
            for (int r4 = 0; r4 < 4; r4++) {
                int rowl = rt * 16 + lg * 4 + r4;
                float2 st = stat[rowl];
                float wv = wss[rowl * 33 + n];
#pragma unroll
                for (int ct = 0; ct < 4; ct++) {
                    float proc = (acc[rt][ct + 4][r4] - st.x) * st.y * lngv[ct] + lnbv[ct];
                    sel[rt][ct][r4] += proc * wv;
                }
            }
        }
    }

    // ---- write selected
#pragma unroll
    for (int rt = 0; rt < 2; rt++)
#pragma unroll
        for (int r4 = 0; r4 < 4; r4++) {
            int row = R0 + rt * 16 + lg * 4 + r4;
#pragma unroll
            for (int ct = 0; ct < 4; ct++)
                out[row * DM + wc * 64 + ct * 16 + l15] = sel[rt][ct][r4];
        }
}

// ---------------------------------------------------------------------------
extern "C" void kernel_launch(void* const* d_in, const int* in_sizes, int n_in,
                              void* d_out, int out_size, void* d_ws, size_t ws_size,
                              hipStream_t stream) {
    const float* x        = (const float*)d_in[0];
    const float* g_fc1_w  = (const float*)d_in[1];
    const float* g_fc1_b  = (const float*)d_in[2];
    const float* g_gate_w = (const float*)d_in[3];
    const float* g_gate_b = (const float*)d_in[4];
    const float* g_fc2_w  = (const float*)d_in[5];
    const float* g_fc2_b  = (const float*)d_in[6];
    const float* g_ln_g   = (const float*)d_in[7];
    const float* g_ln_b   = (const float*)d_in[8];
    const float* f_fc1_w  = (const float*)d_in[9];
    const float* f_fc1_b  = (const float*)d_in[10];
    const float* f_gate_w = (const float*)d_in[11];
    const float* f_gate_b = (const float*)d_in[12];
    const float* f_fc2_w  = (const float*)d_in[13];
    const float* f_fc2_b  = (const float*)d_in[14];
    const float* f_skip_w = (const float*)d_in[15];
    const float* f_skip_b = (const float*)d_in[16];
    const float* f_ln_g   = (const float*)d_in[17];
    const float* f_ln_b   = (const float*)d_in[18];

    float* out_sel = (float*)d_out;                    // [8192][256]
    float* out_fw  = (float*)d_out + BT * DM;          // [16][32]

    // workspace: wsel 1MB + Bfrag 4MB = 5,242,880 B (same as round-0 usage)
    float* ws_w  = (float*)d_ws;                       // [8192][32]
    short* bfrag = (short*)((float*)d_ws + BT * N);    // 2M bf16

    hipMemsetAsync(out_fw, 0, 16 * N * sizeof(float), stream);

    k_pack<<<N * 4, 256, 0, stream>>>(f_gate_w, f_fc2_w, bfrag);

    k_sel<<<BT / 4, 256, 0, stream>>>(x, g_fc1_w, g_fc1_b, g_gate_w, g_gate_b,
                                      g_fc2_w, g_fc2_b, g_ln_g, g_ln_b,
                                      ws_w, out_fw);

    k_feat<<<BT / 32, 256, 0, stream>>>(x, f_fc1_w, f_fc1_b, bfrag,
                                        f_gate_b, f_fc2_b,
                                        f_skip_w, f_skip_b, f_ln_g, f_ln_b,
                                        ws_w, out_sel);
}

// Round 11
// 341.981 us; speedup vs baseline: 1.9400x; 1.1511x over previous
//
#include <hip/hip_runtime.h>
#include <math.h>

// Problem constants (fixed by the reference)
#define N   32
#define DM  256
#define H   64
#define BT  8192          // 16*512 rows
#define T_SEQ 512

typedef __attribute__((ext_vector_type(8))) short bf16x8;   // 8 bf16 = 4 VGPR
typedef __attribute__((ext_vector_type(4))) float f32x4;    // MFMA acc

__device__ __forceinline__ float elu_f(float v) {
    return fmaxf(v, __expf(fminf(v, 0.f)) - 1.f);
}
__device__ __forceinline__ float sigm_f(float v) {
    return 1.f / (1.f + __expf(-v));
}

// split v into truncated-bf16 hi + truncated-bf16 lo (lo = exact residual of hi)
__device__ __forceinline__ void split_pack8(const float* v, bf16x8& hi, bf16x8& lo) {
    unsigned u[8]; float lf[8];
#pragma unroll
    for (int i = 0; i < 8; i++) {
        u[i]  = __builtin_bit_cast(unsigned, v[i]);
        lf[i] = v[i] - __builtin_bit_cast(float, u[i] & 0xffff0000u);
    }
    unsigned hw[4], lw[4];
#pragma unroll
    for (int j = 0; j < 4; j++) {
        hw[j] = (u[2*j] >> 16) | (u[2*j+1] & 0xffff0000u);
        unsigned l0 = __builtin_bit_cast(unsigned, lf[2*j]);
        unsigned l1 = __builtin_bit_cast(unsigned, lf[2*j+1]);
        lw[j] = (l0 >> 16) | (l1 & 0xffff0000u);
    }
    uint4 h4 = make_uint4(hw[0], hw[1], hw[2], hw[3]);
    uint4 l4 = make_uint4(lw[0], lw[1], lw[2], lw[3]);
    hi = __builtin_bit_cast(bf16x8, h4);
    lo = __builtin_bit_cast(bf16x8, l4);
}

// ---------------------------------------------------------------------------
// k_pack: pack f_gate_w / f_fc2_w [N][DM][H] into per-(n,wc) MFMA B-fragments
// (hi/lo split). Fragment (n,wc,ks,ct,s): lane l holds col d = wc*64+(ct&3)*16
// +(l&15) (ct<4 -> gate, ct>=4 -> fc2), k = ks*32+(l>>4)*8+i, value W[n][d][k].
// Layout: ((((n*4+wc)*2+ks)*8+ct)*2+s)*512 + lane*8 + i   (bf16 elements)
// grid = 256 (n, wc, ks) so all CUs participate.
// ---------------------------------------------------------------------------
__global__ __launch_bounds__(256) void k_pack(const float* __restrict__ gw,
                                              const float* __restrict__ fw,
                                              short* __restrict__ bfrag) {
    int blk = blockIdx.x;                   // (n*4 + wc)*2 + ks
    int ks = blk & 1, wc = (blk >> 1) & 3, n = blk >> 3;
    int wid = threadIdx.x >> 6, lane = threadIdx.x & 63;
    for (int ct = wid; ct < 8; ct += 4) {
        const float* W = (ct < 4) ? gw : fw;
        int d  = wc * 64 + (ct & 3) * 16 + (lane & 15);
        int h0 = ks * 32 + (lane >> 4) * 8;
        const float* src = W + (n * DM + d) * H + h0;
        float v[8];
        float4 a = *(const float4*)src;
        float4 b = *(const float4*)(src + 4);
        v[0]=a.x; v[1]=a.y; v[2]=a.z; v[3]=a.w;
        v[4]=b.x; v[5]=b.y; v[6]=b.z; v[7]=b.w;
        bf16x8 hi, lo;
        split_pack8(v, hi, lo);
        short* dst = bfrag + (size_t)((((n*4 + wc)*2 + ks)*8 + ct)*2) * 512 + lane * 8;
        *(bf16x8*)dst         = hi;
        *(bf16x8*)(dst + 512) = lo;
    }
}

// ---------------------------------------------------------------------------
// k_sel: selection GRN, 4 rows per WAVE (16 rows / block, grid 512).
// Weight reads amortized over 4 rows; no atomics (k_fw does feat_weights).
// ---------------------------------------------------------------------------
__global__ __launch_bounds__(256) void k_sel(const float* __restrict__ x,
                      const float* __restrict__ fc1w, const float* __restrict__ fc1b,
                      const float* __restrict__ gatew, const float* __restrict__ gateb,
                      const float* __restrict__ fc2w, const float* __restrict__ fc2b,
                      const float* __restrict__ lng, const float* __restrict__ lnb,
                      float* __restrict__ wsel) {
    int wid = threadIdx.x >> 6, lane = threadIdx.x & 63;
    int l31 = lane & 31;
    int row0 = blockIdx.x * 16 + wid * 4;

    float xv[4];
#pragma unroll
    for (int r = 0; r < 4; r++) xv[r] = x[(row0 + r) * N + l31];

    // h[r][j] = elu(fc1w[dm0+j,:] . x_r + fc1b[dm0+j]), dm0 = lane*4
    int dm0 = lane * 4;
    float4 hb = *(const float4*)(fc1b + dm0);
    float h[4][4];
#pragma unroll
    for (int r = 0; r < 4; r++) { h[r][0]=hb.x; h[r][1]=hb.y; h[r][2]=hb.z; h[r][3]=hb.w; }
#pragma unroll
    for (int c4 = 0; c4 < 8; c4++) {
        float4 w0 = *(const float4*)(fc1w + (dm0 + 0) * N + c4 * 4);
        float4 w1 = *(const float4*)(fc1w + (dm0 + 1) * N + c4 * 4);
        float4 w2 = *(const float4*)(fc1w + (dm0 + 2) * N + c4 * 4);
        float4 w3 = *(const float4*)(fc1w + (dm0 + 3) * N + c4 * 4);
#pragma unroll
        for (int r = 0; r < 4; r++) {
            float xb0 = __shfl(xv[r], c4 * 4 + 0);
            float xb1 = __shfl(xv[r], c4 * 4 + 1);
            float xb2 = __shfl(xv[r], c4 * 4 + 2);
            float xb3 = __shfl(xv[r], c4 * 4 + 3);
            h[r][0] += w0.x * xb0 + w0.y * xb1 + w0.z * xb2 + w0.w * xb3;
            h[r][1] += w1.x * xb0 + w1.y * xb1 + w1.z * xb2 + w1.w * xb3;
            h[r][2] += w2.x * xb0 + w2.y * xb1 + w2.z * xb2 + w2.w * xb3;
            h[r][3] += w3.x * xb0 + w3.y * xb1 + w3.z * xb2 + w3.w * xb3;
        }
    }
#pragma unroll
    for (int r = 0; r < 4; r++)
#pragma unroll
        for (int j = 0; j < 4; j++) h[r][j] = elu_f(h[r][j]);

    // a[n], h2[n] via per-n dot + 64-lane butterfly; lane l31 keeps n==l31
    float av[4], bv[4];
#pragma unroll
    for (int nn = 0; nn < N; nn++) {
        float4 g = *(const float4*)(gatew + nn * DM + dm0);
        float4 f = *(const float4*)(fc2w  + nn * DM + dm0);
#pragma unroll
        for (int r = 0; r < 4; r++) {
            float pa = g.x * h[r][0] + g.y * h[r][1] + g.z * h[r][2] + g.w * h[r][3];
            float pb = f.x * h[r][0] + f.y * h[r][1] + f.z * h[r][2] + f.w * h[r][3];
#pragma unroll
            for (int m = 1; m < 64; m <<= 1) {
                pa += __shfl_xor(pa, m);
                pb += __shfl_xor(pb, m);
            }
            if (l31 == nn) { av[r] = pa; bv[r] = pb; }
        }
    }

    float gb_ = gateb[l31], fb_ = fc2b[l31], lgv = lng[l31], lbv = lnb[l31];
#pragma unroll
    for (int r = 0; r < 4; r++) {
        float a  = sigm_f(av[r] + gb_);
        float b2 = bv[r] + fb_;
        float y  = a * b2 + xv[r];
        float s1 = y, s2 = y * y;
#pragma unroll
        for (int m = 1; m < 32; m <<= 1) { s1 += __shfl_xor(s1, m); s2 += __shfl_xor(s2, m); }
        float mean = s1 * (1.f / 32.f);
        float var  = s2 * (1.f / 32.f) - mean * mean;
        float xn = (y - mean) * rsqrtf(var + 1e-5f) * lgv + lbv;
        float mx = xn;
#pragma unroll
        for (int m = 1; m < 32; m <<= 1) mx = fmaxf(mx, __shfl_xor(mx, m));
        float e = __expf(xn - mx);
        float es = e;
#pragma unroll
        for (int m = 1; m < 32; m <<= 1) es += __shfl_xor(es, m);
        float w = e / es;
        if (lane < 32) wsel[(row0 + r) * N + l31] = w;
    }
}

// ---------------------------------------------------------------------------
// k_fw: feat_weights[b][n] = mean over T of wsel. 16 blocks, no atomics.
// ---------------------------------------------------------------------------
__global__ __launch_bounds__(256) void k_fw(const float* __restrict__ wsel,
                                            float* __restrict__ fwout) {
    __shared__ float part[8][32];
    int b = blockIdx.x, t = threadIdx.x;
    int n = t & 31, rg = t >> 5;
    float s = 0.f;
#pragma unroll 8
    for (int j = 0; j < 64; j++) {
        int r = rg + j * 8;
        s += wsel[(b * T_SEQ + r) * N + n];
    }
    part[rg][n] = s;
    __syncthreads();
    if (t < 32) {
        float tot = 0.f;
#pragma unroll
        for (int i = 0; i < 8; i++) tot += part[i][t];
        fwout[b * N + t] = tot * (1.f / (float)T_SEQ);
    }
}

// ---------------------------------------------------------------------------
// k_feat: per-feature GRNs via split-bf16 MFMA.
// Grid 512 x 256 thr; block owns 16 rows; wave wc owns d-slice
// [wc*64, wc*64+64) carrying gate (ct 0..3) AND fc2 (ct 4..7) columns.
// One barrier per n-iter via double-buffered LN-partial exchange.
// ---------------------------------------------------------------------------
__global__ __launch_bounds__(256, 2) void k_feat(
        const float* __restrict__ x,
        const float* __restrict__ f1w, const float* __restrict__ f1b,
        const short* __restrict__ bfrag,
        const float* __restrict__ gb,  const float* __restrict__ fb,
        const float* __restrict__ skw, const float* __restrict__ skb,
        const float* __restrict__ lng, const float* __restrict__ lnb,
        const float* __restrict__ wsel, float* __restrict__ out) {
    __shared__ float  xs[16 * 33];
    __shared__ float  wss[16 * 33];
    __shared__ float2 part[2][4][16];

    int t = threadIdx.x;
    int wc = t >> 6, lane = t & 63;
    int l15 = lane & 15, lg = lane >> 4;
    int R0 = blockIdx.x * 16;

    // stage x rows + selection weights (512 elems, 2 per thread)
#pragma unroll
    for (int i = 0; i < 2; i++) {
        int idx = i * 256 + t;              // 0..511
        int r = idx >> 5, c = idx & 31;
        xs[r * 33 + c]  = x[(R0 + r) * N + c];
        wss[r * 33 + c] = wsel[(R0 + r) * N + c];
    }
    __syncthreads();

    f32x4 sel[4];
#pragma unroll
    for (int ct = 0; ct < 4; ct++) sel[ct] = (f32x4)(0.f);

    const short* bwc = bfrag + (size_t)(wc * 2) * 8 * 2 * 512;

#pragma unroll 1
    for (int n = 0; n < N; n++) {
        // ---- per-(n,d) constants for this wave's d-slice
        int dbase = n * DM + wc * 64 + l15;
        float gbv[4], fbv[4], skwv[4], skbv[4], lngv[4], lnbv[4];
#pragma unroll
        for (int ct = 0; ct < 4; ct++) {
            gbv[ct]  = gb [dbase + ct * 16];
            fbv[ct]  = fb [dbase + ct * 16];
            skwv[ct] = skw[dbase + ct * 16];
            skbv[ct] = skb[dbase + ct * 16];
            lngv[ct] = lng[dbase + ct * 16];
            lnbv[ct] = lnb[dbase + ct * 16];
        }

        // ---- A fragments: hf = elu(x*f1w+f1b), split hi/lo; row = l15
        bf16x8 ahi[2], alo[2];
#pragma unroll
        for (int ks = 0; ks < 2; ks++) {
            int h0 = ks * 32 + lg * 8;
            float4 w0 = *(const float4*)(f1w + n * H + h0);
            float4 w1 = *(const float4*)(f1w + n * H + h0 + 4);
            float4 b0 = *(const float4*)(f1b + n * H + h0);
            float4 b1 = *(const float4*)(f1b + n * H + h0 + 4);
            float xa = xs[l15 * 33 + n];
            float v[8];
            v[0] = elu_f(xa * w0.x + b0.x);
            v[1] = elu_f(xa * w0.y + b0.y);
            v[2] = elu_f(xa * w0.z + b0.z);
            v[3] = elu_f(xa * w0.w + b0.w);
            v[4] = elu_f(xa * w1.x + b1.x);
            v[5] = elu_f(xa * w1.y + b1.y);
            v[6] = elu_f(xa * w1.z + b1.z);
            v[7] = elu_f(xa * w1.w + b1.w);
            split_pack8(v, ahi[ks], alo[ks]);
        }

        // ---- MFMA: acc[ct] ; ct<4 gate (init gate bias), ct>=4 fc2
        f32x4 acc[8];
#pragma unroll
        for (int ct = 0; ct < 8; ct++)
            acc[ct] = (f32x4)(ct < 4 ? gbv[ct] : fbv[ct - 4]);

        const short* bn = bwc + (size_t)n * 4 * 2 * 8 * 2 * 512;
#pragma unroll
        for (int ks = 0; ks < 2; ks++) {
#pragma unroll
            for (int ct = 0; ct < 8; ct++) {
                const short* bp = bn + ((ks * 8 + ct) * 2) * 512 + lane * 8;
                bf16x8 bhi = *(const bf16x8*)bp;
                bf16x8 blo = *(const bf16x8*)(bp + 512);
                acc[ct] = __builtin_amdgcn_mfma_f32_16x16x32_bf16(ahi[ks], bhi, acc[ct], 0, 0, 0);
                acc[ct] = __builtin_amdgcn_mfma_f32_16x16x32_bf16(alo[ks], bhi, acc[ct], 0, 0, 0);
                acc[ct] = __builtin_amdgcn_mfma_f32_16x16x32_bf16(ahi[ks], blo, acc[ct], 0, 0, 0);
            }
        }

        // ---- epilogue: y = sig(gate)*fc2 + x*skw+skb ; LN partials; C row = lg*4+r4
        int buf = n & 1;
#pragma unroll
        for (int r4 = 0; r4 < 4; r4++) {
            int rowl = lg * 4 + r4;
            float xa = xs[rowl * 33 + n];
            float s1 = 0.f, s2 = 0.f;
#pragma unroll
            for (int ct = 0; ct < 4; ct++) {
                float a  = sigm_f(acc[ct][r4]);
                float yy = a * acc[ct + 4][r4] + xa * skwv[ct] + skbv[ct];
                acc[ct + 4][r4] = yy;   // keep y in acc storage
                s1 += yy; s2 += yy * yy;
            }
#pragma unroll
            for (int m = 1; m < 16; m <<= 1) {
                s1 += __shfl_xor(s1, m);
                s2 += __shfl_xor(s2, m);
            }
            if (l15 == 0) part[buf][wc][rowl] = make_float2(s1, s2);
        }
        __syncthreads();

        // ---- stats (recomputed per wave from 4 partials) ; sel += proc * w
#pragma unroll
        for (int r4 = 0; r4 < 4; r4++) {
            int rowl = lg * 4 + r4;
            float s1 = part[buf][0][rowl].x + part[buf][1][rowl].x
                     + part[buf][2][rowl].x + part[buf][3][rowl].x;
            float s2 = part[buf][0][rowl].y + part[buf][1][rowl].y
                     + part[buf][2][rowl].y + part[buf][3][rowl].y;
            float mean = s1 * (1.f / (float)DM);
            float var  = s2 * (1.f / (float)DM) - mean * mean;
            float rs = rsqrtf(var + 1e-5f);
            float wv = wss[rowl * 33 + n];
#pragma unroll
            for (int ct = 0; ct < 4; ct++) {
                float proc = (acc[ct + 4][r4] - mean) * rs * lngv[ct] + lnbv[ct];
                sel[ct][r4] += proc * wv;
            }
        }
    }

    // ---- write selected
#pragma unroll
    for (int r4 = 0; r4 < 4; r4++) {
        int row = R0 + lg * 4 + r4;
#pragma unroll
        for (int ct = 0; ct < 4; ct++)
            out[row * DM + wc * 64 + ct * 16 + l15] = sel[ct][r4];
    }
}

// ---------------------------------------------------------------------------
extern "C" void kernel_launch(void* const* d_in, const int* in_sizes, int n_in,
                              void* d_out, int out_size, void* d_ws, size_t ws_size,
                              hipStream_t stream) {
    const float* x        = (const float*)d_in[0];
    const float* g_fc1_w  = (const float*)d_in[1];
    const float* g_fc1_b  = (const float*)d_in[2];
    const float* g_gate_w = (const float*)d_in[3];
    const float* g_gate_b = (const float*)d_in[4];
    const float* g_fc2_w  = (const float*)d_in[5];
    const float* g_fc2_b  = (const float*)d_in[6];
    const float* g_ln_g   = (const float*)d_in[7];
    const float* g_ln_b   = (const float*)d_in[8];
    const float* f_fc1_w  = (const float*)d_in[9];
    const float* f_fc1_b  = (const float*)d_in[10];
    const float* f_gate_w = (const float*)d_in[11];
    const float* f_gate_b = (const float*)d_in[12];
    const float* f_fc2_w  = (const float*)d_in[13];
    const float* f_fc2_b  = (const float*)d_in[14];
    const float* f_skip_w = (const float*)d_in[15];
    const float* f_skip_b = (const float*)d_in[16];
    const float* f_ln_g   = (const float*)d_in[17];
    const float* f_ln_b   = (const float*)d_in[18];

    float* out_sel = (float*)d_out;                    // [8192][256]
    float* out_fw  = (float*)d_out + BT * DM;          // [16][32]

    // workspace: wsel 1MB + Bfrag 4MB = 5,242,880 B
    float* ws_w  = (float*)d_ws;                       // [8192][32]
    short* bfrag = (short*)((float*)d_ws + BT * N);    // 2M bf16

    k_pack<<<256, 256, 0, stream>>>(f_gate_w, f_fc2_w, bfrag);

    k_sel<<<BT / 16, 256, 0, stream>>>(x, g_fc1_w, g_fc1_b, g_gate_w, g_gate_b,
                                       g_fc2_w, g_fc2_b, g_ln_g, g_ln_b,
                                       ws_w);

    k_fw<<<16, 256, 0, stream>>>(ws_w, out_fw);

    k_feat<<<BT / 16, 256, 0, stream>>>(x, f_fc1_w, f_fc1_b, bfrag,
                                        f_gate_b, f_fc2_b,
                                        f_skip_w, f_skip_b, f_ln_g, f_ln_b,
                                        ws_w, out_sel);
}

// Round 12
// 333.263 us; speedup vs baseline: 1.9908x; 1.0262x over previous
//
#include <hip/hip_runtime.h>
#include <math.h>

// Problem constants (fixed by the reference)
#define N   32
#define DM  256
#define H   64
#define BT  8192          // 16*512 rows
#define T_SEQ 512

typedef __attribute__((ext_vector_type(8))) short bf16x8;   // 8 bf16 = 4 VGPR
typedef __attribute__((ext_vector_type(4))) float f32x4;    // MFMA acc

__device__ __forceinline__ float elu_f(float v) {
    return fmaxf(v, __expf(fminf(v, 0.f)) - 1.f);
}
__device__ __forceinline__ float sigm_f(float v) {
    return 1.f / (1.f + __expf(-v));
}

// split v into truncated-bf16 hi + truncated-bf16 lo (lo = exact residual of hi)
__device__ __forceinline__ void split_pack8(const float* v, bf16x8& hi, bf16x8& lo) {
    unsigned u[8]; float lf[8];
#pragma unroll
    for (int i = 0; i < 8; i++) {
        u[i]  = __builtin_bit_cast(unsigned, v[i]);
        lf[i] = v[i] - __builtin_bit_cast(float, u[i] & 0xffff0000u);
    }
    unsigned hw[4], lw[4];
#pragma unroll
    for (int j = 0; j < 4; j++) {
        hw[j] = (u[2*j] >> 16) | (u[2*j+1] & 0xffff0000u);
        unsigned l0 = __builtin_bit_cast(unsigned, lf[2*j]);
        unsigned l1 = __builtin_bit_cast(unsigned, lf[2*j+1]);
        lw[j] = (l0 >> 16) | (l1 & 0xffff0000u);
    }
    uint4 h4 = make_uint4(hw[0], hw[1], hw[2], hw[3]);
    uint4 l4 = make_uint4(lw[0], lw[1], lw[2], lw[3]);
    hi = __builtin_bit_cast(bf16x8, h4);
    lo = __builtin_bit_cast(bf16x8, l4);
}

// ---------------------------------------------------------------------------
// k_pack: pack f_gate_w / f_fc2_w [N][DM][H] into per-(n,wc) MFMA B-fragments
// (hi/lo split). Fragment (n,wc,ks,ct,s): lane l holds col d = wc*64+(ct&3)*16
// +(l&15) (ct<4 -> gate, ct>=4 -> fc2), k = ks*32+(l>>4)*8+i, value W[n][d][k].
// Layout: ((((n*4+wc)*2+ks)*8+ct)*2+s)*512 + lane*8 + i   (bf16 elements)
// grid = 256 (n, wc, ks) so all CUs participate.  (UNCHANGED since round 3)
// ---------------------------------------------------------------------------
__global__ __launch_bounds__(256) void k_pack(const float* __restrict__ gw,
                                              const float* __restrict__ fw,
                                              short* __restrict__ bfrag) {
    int blk = blockIdx.x;                   // (n*4 + wc)*2 + ks
    int ks = blk & 1, wc = (blk >> 1) & 3, n = blk >> 3;
    int wid = threadIdx.x >> 6, lane = threadIdx.x & 63;
    for (int ct = wid; ct < 8; ct += 4) {
        const float* W = (ct < 4) ? gw : fw;
        int d  = wc * 64 + (ct & 3) * 16 + (lane & 15);
        int h0 = ks * 32 + (lane >> 4) * 8;
        const float* src = W + (n * DM + d) * H + h0;
        float v[8];
        float4 a = *(const float4*)src;
        float4 b = *(const float4*)(src + 4);
        v[0]=a.x; v[1]=a.y; v[2]=a.z; v[3]=a.w;
        v[4]=b.x; v[5]=b.y; v[6]=b.z; v[7]=b.w;
        bf16x8 hi, lo;
        split_pack8(v, hi, lo);
        short* dst = bfrag + (size_t)((((n*4 + wc)*2 + ks)*8 + ct)*2) * 512 + lane * 8;
        *(bf16x8*)dst         = hi;
        *(bf16x8*)(dst + 512) = lo;
    }
}

// ---------------------------------------------------------------------------
// k_sel: selection GRN, 4 rows per WAVE (16 rows / block, grid 512).
// (UNCHANGED since round 3 — suspect for the 127us tail; rewrite pending
//  per-dispatch timing evidence.)
// ---------------------------------------------------------------------------
__global__ __launch_bounds__(256) void k_sel(const float* __restrict__ x,
                      const float* __restrict__ fc1w, const float* __restrict__ fc1b,
                      const float* __restrict__ gatew, const float* __restrict__ gateb,
                      const float* __restrict__ fc2w, const float* __restrict__ fc2b,
                      const float* __restrict__ lng, const float* __restrict__ lnb,
                      float* __restrict__ wsel) {
    int wid = threadIdx.x >> 6, lane = threadIdx.x & 63;
    int l31 = lane & 31;
    int row0 = blockIdx.x * 16 + wid * 4;

    float xv[4];
#pragma unroll
    for (int r = 0; r < 4; r++) xv[r] = x[(row0 + r) * N + l31];

    // h[r][j] = elu(fc1w[dm0+j,:] . x_r + fc1b[dm0+j]), dm0 = lane*4
    int dm0 = lane * 4;
    float4 hb = *(const float4*)(fc1b + dm0);
    float h[4][4];
#pragma unroll
    for (int r = 0; r < 4; r++) { h[r][0]=hb.x; h[r][1]=hb.y; h[r][2]=hb.z; h[r][3]=hb.w; }
#pragma unroll
    for (int c4 = 0; c4 < 8; c4++) {
        float4 w0 = *(const float4*)(fc1w + (dm0 + 0) * N + c4 * 4);
        float4 w1 = *(const float4*)(fc1w + (dm0 + 1) * N + c4 * 4);
        float4 w2 = *(const float4*)(fc1w + (dm0 + 2) * N + c4 * 4);
        float4 w3 = *(const float4*)(fc1w + (dm0 + 3) * N + c4 * 4);
#pragma unroll
        for (int r = 0; r < 4; r++) {
            float xb0 = __shfl(xv[r], c4 * 4 + 0);
            float xb1 = __shfl(xv[r], c4 * 4 + 1);
            float xb2 = __shfl(xv[r], c4 * 4 + 2);
            float xb3 = __shfl(xv[r], c4 * 4 + 3);
            h[r][0] += w0.x * xb0 + w0.y * xb1 + w0.z * xb2 + w0.w * xb3;
            h[r][1] += w1.x * xb0 + w1.y * xb1 + w1.z * xb2 + w1.w * xb3;
            h[r][2] += w2.x * xb0 + w2.y * xb1 + w2.z * xb2 + w2.w * xb3;
            h[r][3] += w3.x * xb0 + w3.y * xb1 + w3.z * xb2 + w3.w * xb3;
        }
    }
#pragma unroll
    for (int r = 0; r < 4; r++)
#pragma unroll
        for (int j = 0; j < 4; j++) h[r][j] = elu_f(h[r][j]);

    // a[n], h2[n] via per-n dot + 64-lane butterfly; lane l31 keeps n==l31
    float av[4], bv[4];
#pragma unroll
    for (int nn = 0; nn < N; nn++) {
        float4 g = *(const float4*)(gatew + nn * DM + dm0);
        float4 f = *(const float4*)(fc2w  + nn * DM + dm0);
#pragma unroll
        for (int r = 0; r < 4; r++) {
            float pa = g.x * h[r][0] + g.y * h[r][1] + g.z * h[r][2] + g.w * h[r][3];
            float pb = f.x * h[r][0] + f.y * h[r][1] + f.z * h[r][2] + f.w * h[r][3];
#pragma unroll
            for (int m = 1; m < 64; m <<= 1) {
                pa += __shfl_xor(pa, m);
                pb += __shfl_xor(pb, m);
            }
            if (l31 == nn) { av[r] = pa; bv[r] = pb; }
        }
    }

    float gb_ = gateb[l31], fb_ = fc2b[l31], lgv = lng[l31], lbv = lnb[l31];
#pragma unroll
    for (int r = 0; r < 4; r++) {
        float a  = sigm_f(av[r] + gb_);
        float b2 = bv[r] + fb_;
        float y  = a * b2 + xv[r];
        float s1 = y, s2 = y * y;
#pragma unroll
        for (int m = 1; m < 32; m <<= 1) { s1 += __shfl_xor(s1, m); s2 += __shfl_xor(s2, m); }
        float mean = s1 * (1.f / 32.f);
        float var  = s2 * (1.f / 32.f) - mean * mean;
        float xn = (y - mean) * rsqrtf(var + 1e-5f) * lgv + lbv;
        float mx = xn;
#pragma unroll
        for (int m = 1; m < 32; m <<= 1) mx = fmaxf(mx, __shfl_xor(mx, m));
        float e = __expf(xn - mx);
        float es = e;
#pragma unroll
        for (int m = 1; m < 32; m <<= 1) es += __shfl_xor(es, m);
        float w = e / es;
        if (lane < 32) wsel[(row0 + r) * N + l31] = w;
    }
}

// ---------------------------------------------------------------------------
// k_fw: feat_weights[b][n] = mean over T of wsel. 16 blocks, no atomics.
// ---------------------------------------------------------------------------
__global__ __launch_bounds__(256) void k_fw(const float* __restrict__ wsel,
                                            float* __restrict__ fwout) {
    __shared__ float part[8][32];
    int b = blockIdx.x, t = threadIdx.x;
    int n = t & 31, rg = t >> 5;
    float s = 0.f;
#pragma unroll 8
    for (int j = 0; j < 64; j++) {
        int r = rg + j * 8;
        s += wsel[(b * T_SEQ + r) * N + n];
    }
    part[rg][n] = s;
    __syncthreads();
    if (t < 32) {
        float tot = 0.f;
#pragma unroll
        for (int i = 0; i < 8; i++) tot += part[i][t];
        fwout[b * N + t] = tot * (1.f / (float)T_SEQ);
    }
}

// ---------------------------------------------------------------------------
// k_feat: per-feature GRNs via split-bf16 MFMA.
// NEW: 512 threads = 8 waves per block; block owns 16 rows (grid 512
// unchanged) -> 16 waves/CU (2 blocks x 8 waves), double round-11's 8.
// Wave w owns 32 d-cols = column groups (wc = w>>1, ctl in {2*(w&1), +1}),
// carrying gate and fc2 for those cols. Per-wave work halves; B-frag layout
// and k_pack unchanged. LN partial exchange widens to 8 waves.
// ---------------------------------------------------------------------------
__global__ __launch_bounds__(512, 4) void k_feat(
        const float* __restrict__ x,
        const float* __restrict__ f1w, const float* __restrict__ f1b,
        const short* __restrict__ bfrag,
        const float* __restrict__ gb,  const float* __restrict__ fb,
        const float* __restrict__ skw, const float* __restrict__ skb,
        const float* __restrict__ lng, const float* __restrict__ lnb,
        const float* __restrict__ wsel, float* __restrict__ out) {
    __shared__ float  xs[16 * 33];
    __shared__ float  wss[16 * 33];
    __shared__ float2 part[2][8][16];

    int t = threadIdx.x;
    int w = t >> 6, lane = t & 63;
    int l15 = lane & 15, lg = lane >> 4;
    int R0 = blockIdx.x * 16;

    int wc   = w >> 1;             // 64-col slice of the packed layout
    int ctl0 = (w & 1) * 2;        // owned ct-low values: ctl0, ctl0+1

    // stage x rows + selection weights (512 elems, 1 per thread)
    {
        int r = t >> 5, c = t & 31;
        xs[r * 33 + c]  = x[(R0 + r) * N + c];
        wss[r * 33 + c] = wsel[(R0 + r) * N + c];
    }
    __syncthreads();

    f32x4 sel[2];
    sel[0] = (f32x4)(0.f);
    sel[1] = (f32x4)(0.f);

    const short* bwc = bfrag + (size_t)(wc * 2) * 8 * 2 * 512;

#pragma unroll 1
    for (int n = 0; n < N; n++) {
        // ---- per-(n,d) constants for this wave's 2 column groups
        int dbase = n * DM + wc * 64 + l15;
        float gbv[2], fbv[2], skwv[2], skbv[2], lngv[2], lnbv[2];
#pragma unroll
        for (int j = 0; j < 2; j++) {
            int off = dbase + (ctl0 + j) * 16;
            gbv[j]  = gb [off];
            fbv[j]  = fb [off];
            skwv[j] = skw[off];
            skbv[j] = skb[off];
            lngv[j] = lng[off];
            lnbv[j] = lnb[off];
        }

        // ---- A fragments: hf = elu(x*f1w+f1b), split hi/lo; row = l15
        // (identical across the 8 waves; redundant compute, no barrier)
        bf16x8 ahi[2], alo[2];
#pragma unroll
        for (int ks = 0; ks < 2; ks++) {
            int h0 = ks * 32 + lg * 8;
            float4 w0 = *(const float4*)(f1w + n * H + h0);
            float4 w1 = *(const float4*)(f1w + n * H + h0 + 4);
            float4 b0 = *(const float4*)(f1b + n * H + h0);
            float4 b1 = *(const float4*)(f1b + n * H + h0 + 4);
            float xa = xs[l15 * 33 + n];
            float v[8];
            v[0] = elu_f(xa * w0.x + b0.x);
            v[1] = elu_f(xa * w0.y + b0.y);
            v[2] = elu_f(xa * w0.z + b0.z);
            v[3] = elu_f(xa * w0.w + b0.w);
            v[4] = elu_f(xa * w1.x + b1.x);
            v[5] = elu_f(xa * w1.y + b1.y);
            v[6] = elu_f(xa * w1.z + b1.z);
            v[7] = elu_f(xa * w1.w + b1.w);
            split_pack8(v, ahi[ks], alo[ks]);
        }

        // ---- MFMA: acc[j][0]=gate, acc[j][1]=fc2 for group j
        f32x4 acc[2][2];
#pragma unroll
        for (int j = 0; j < 2; j++) {
            acc[j][0] = (f32x4)(gbv[j]);
            acc[j][1] = (f32x4)(fbv[j]);
        }

        const short* bn = bwc + (size_t)n * 4 * 2 * 8 * 2 * 512;
#pragma unroll
        for (int ks = 0; ks < 2; ks++) {
#pragma unroll
            for (int j = 0; j < 2; j++) {
#pragma unroll
                for (int gf = 0; gf < 2; gf++) {
                    int ct = ctl0 + j + gf * 4;   // gate: ctl, fc2: ctl+4
                    const short* bp = bn + ((ks * 8 + ct) * 2) * 512 + lane * 8;
                    bf16x8 bhi = *(const bf16x8*)bp;
                    bf16x8 blo = *(const bf16x8*)(bp + 512);
                    acc[j][gf] = __builtin_amdgcn_mfma_f32_16x16x32_bf16(ahi[ks], bhi, acc[j][gf], 0, 0, 0);
                    acc[j][gf] = __builtin_amdgcn_mfma_f32_16x16x32_bf16(alo[ks], bhi, acc[j][gf], 0, 0, 0);
                    acc[j][gf] = __builtin_amdgcn_mfma_f32_16x16x32_bf16(ahi[ks], blo, acc[j][gf], 0, 0, 0);
                }
            }
        }

        // ---- epilogue: y = sig(gate)*fc2 + x*skw+skb ; LN partials over
        //      this wave's 32 cols (2 groups x 16 lanes); C row = lg*4+r4
        int buf = n & 1;
#pragma unroll
        for (int r4 = 0; r4 < 4; r4++) {
            int rowl = lg * 4 + r4;
            float xa = xs[rowl * 33 + n];
            float s1 = 0.f, s2 = 0.f;
#pragma unroll
            for (int j = 0; j < 2; j++) {
                float a  = sigm_f(acc[j][0][r4]);
                float yy = a * acc[j][1][r4] + xa * skwv[j] + skbv[j];
                acc[j][1][r4] = yy;   // keep y in acc storage
                s1 += yy; s2 += yy * yy;
            }
#pragma unroll
            for (int m = 1; m < 16; m <<= 1) {
                s1 += __shfl_xor(s1, m);
                s2 += __shfl_xor(s2, m);
            }
            if (l15 == 0) part[buf][w][rowl] = make_float2(s1, s2);
        }
        __syncthreads();

        // ---- stats (sum 8 wave-partials) ; sel += proc * w
#pragma unroll
        for (int r4 = 0; r4 < 4; r4++) {
            int rowl = lg * 4 + r4;
            float s1 = 0.f, s2 = 0.f;
#pragma unroll
            for (int i = 0; i < 8; i++) {
                float2 p = part[buf][i][rowl];
                s1 += p.x; s2 += p.y;
            }
            float mean = s1 * (1.f / (float)DM);
            float var  = s2 * (1.f / (float)DM) - mean * mean;
            float rs = rsqrtf(var + 1e-5f);
            float wv = wss[rowl * 33 + n];
#pragma unroll
            for (int j = 0; j < 2; j++) {
                float proc = (acc[j][1][r4] - mean) * rs * lngv[j] + lnbv[j];
                sel[j][r4] += proc * wv;
            }
        }
    }

    // ---- write selected
#pragma unroll
    for (int r4 = 0; r4 < 4; r4++) {
        int row = R0 + lg * 4 + r4;
#pragma unroll
        for (int j = 0; j < 2; j++)
            out[row * DM + wc * 64 + (ctl0 + j) * 16 + l15] = sel[j][r4];
    }
}

// ---------------------------------------------------------------------------
extern "C" void kernel_launch(void* const* d_in, const int* in_sizes, int n_in,
                              void* d_out, int out_size, void* d_ws, size_t ws_size,
                              hipStream_t stream) {
    const float* x        = (const float*)d_in[0];
    const float* g_fc1_w  = (const float*)d_in[1];
    const float* g_fc1_b  = (const float*)d_in[2];
    const float* g_gate_w = (const float*)d_in[3];
    const float* g_gate_b = (const float*)d_in[4];
    const float* g_fc2_w  = (const float*)d_in[5];
    const float* g_fc2_b  = (const float*)d_in[6];
    const float* g_ln_g   = (const float*)d_in[7];
    const float* g_ln_b   = (const float*)d_in[8];
    const float* f_fc1_w  = (const float*)d_in[9];
    const float* f_fc1_b  = (const float*)d_in[10];
    const float* f_gate_w = (const float*)d_in[11];
    const float* f_gate_b = (const float*)d_in[12];
    const float* f_fc2_w  = (const float*)d_in[13];
    const float* f_fc2_b  = (const float*)d_in[14];
    const float* f_skip_w = (const float*)d_in[15];
    const float* f_skip_b = (const float*)d_in[16];
    const float* f_ln_g   = (const float*)d_in[17];
    const float* f_ln_b   = (const float*)d_in[18];

    float* out_sel = (float*)d_out;                    // [8192][256]
    float* out_fw  = (float*)d_out + BT * DM;          // [16][32]

    // workspace: wsel 1MB + Bfrag 4MB = 5,242,880 B
    float* ws_w  = (float*)d_ws;                       // [8192][32]
    short* bfrag = (short*)((float*)d_ws + BT * N);    // 2M bf16

    k_pack<<<256, 256, 0, stream>>>(f_gate_w, f_fc2_w, bfrag);

    k_sel<<<BT / 16, 256, 0, stream>>>(x, g_fc1_w, g_fc1_b, g_gate_w, g_gate_b,
                                       g_fc2_w, g_fc2_b, g_ln_g, g_ln_b,
                                       ws_w);

    k_fw<<<16, 256, 0, stream>>>(ws_w, out_fw);

    k_feat<<<BT / 16, 512, 0, stream>>>(x, f_fc1_w, f_fc1_b, bfrag,
                                        f_gate_b, f_fc2_b,
                                        f_skip_w, f_skip_b, f_ln_g, f_ln_b,
                                        ws_w, out_sel);
}